// Round 6
// baseline (1671.360 us; speedup 1.0000x reference)
//
#include <hip/hip_runtime.h>

#define C 19
#define DCH 128
#define HWSZ 65536
#define TPB 256

// ws float offsets
#define WS_SUMS  0      // 2432 floats: sums[d*19+c]
#define WS_CNT   2432   // 19
#define WS_VAR   2451   // 19
#define WS_TKT1  2470   // int ticket for k1 tail
#define WS_TKT2  2471   // int ticket for k3 tail
#define WS_ZERO_END 2472
#define WS_MEANS 2560   // 2432: means[d*19+c]
#define WS_VALID 4992   // 19
#define WS_SCAL  5011   // 3: loss_reg, loss_dist, t

#define AGENT_LOAD(p) __hip_atomic_load((p), __ATOMIC_RELAXED, __HIP_MEMORY_SCOPE_AGENT)

// ---------------------------------------------------------------------------
// Dispatch structure (3 total):
//   memset  : zero sums/cnt/var/tickets (9.9 KB)
//   k1_sums : per-class sums+counts; LAST-BLOCK TAIL runs means/valid/reg/dist
//   k3_var  : per-pixel hinged distance; LAST-BLOCK TAIL runs the final scalar
//
// amdgpu_waves_per_eu(4,4): Round-5 post-mortem — with the default heuristic,
// appending the cold tail made hipcc allocate VGPR=32 (occupancy-max), which
// serialized the 8-deep load batch (k3: 378us, 358 GB/s, VALUBusy 2% =
// latency-bound). Pinning occupancy at 4 waves/EU (16/CU, VGPR budget 128)
// removes the incentive to shrink and restores memory-level parallelism.
// ---------------------------------------------------------------------------
#define K1_NB  1024
#define K1_RPX 4096

__global__ __launch_bounds__(TPB)
__attribute__((amdgpu_waves_per_eu(4, 4)))
void k1_sums(const float* __restrict__ feats,
             const int* __restrict__ labels,
             float* __restrict__ ws) {
    __shared__ union {
        int llab[K1_RPX];                     // main phase: 16 KB labels
        struct {                              // tail phase (old k2)
            float lm[DCH * C];
            float lcnt[C];
            float lvalid[C];
            float lreg, ldist, ltv;
            int   llast;
        } p2;
    } sh;
    __shared__ int is_last;

    const int t = threadIdx.x;
    const int lane = t & 63;
    const int w = t >> 6;
    const int bid = blockIdx.x;
    const int b  = bid >> 7;          // 128 blocks per image
    const int r  = (bid >> 3) & 15;   // 16 ranges of 4096 px
    const int dg = bid & 7;           // 8 d-groups of 16 planes

    // stage labels (coalesced int4), keep own 16 in regs for counting
    const int* lb = labels + b * HWSZ + r * K1_RPX;
    int4 myl[4];
#pragma unroll
    for (int u = 0; u < 4; ++u) {
        int4 v = *reinterpret_cast<const int4*>(lb + (u * TPB + t) * 4);
        myl[u] = v;
        *reinterpret_cast<int4*>(&sh.llab[(u * TPB + t) * 4]) = v;
    }
    __syncthreads();

    // counts: only dg==0 blocks contribute
    if (dg == 0) {
        float cr[C];
#pragma unroll
        for (int c = 0; c < C; ++c) cr[c] = 0.f;
#pragma unroll
        for (int u = 0; u < 4; ++u) {
#pragma unroll
            for (int c = 0; c < C; ++c) {
                cr[c] += (myl[u].x == c ? 1.f : 0.f);
                cr[c] += (myl[u].y == c ? 1.f : 0.f);
                cr[c] += (myl[u].z == c ? 1.f : 0.f);
                cr[c] += (myl[u].w == c ? 1.f : 0.f);
            }
        }
#pragma unroll
        for (int c = 0; c < C; ++c)
            for (int m = 1; m < 64; m <<= 1) cr[c] += __shfl_xor(cr[c], m);
        float v = cr[0];
#pragma unroll
        for (int c = 1; c < C; ++c) v = (lane == c) ? cr[c] : v;
        if (lane < C) atomicAdd(&ws[WS_CNT + lane], v);
    }

    // four consecutive d-planes per wave; one-hot shared across all 4
    const int dbase = dg * 16 + w * 4;
    const float* fp0 = feats + (((size_t)(b * DCH + dbase + 0)) << 16) + r * K1_RPX;
    const float* fp1 = feats + (((size_t)(b * DCH + dbase + 1)) << 16) + r * K1_RPX;
    const float* fp2 = feats + (((size_t)(b * DCH + dbase + 2)) << 16) + r * K1_RPX;
    const float* fp3 = feats + (((size_t)(b * DCH + dbase + 3)) << 16) + r * K1_RPX;

    float acc[4][C];
#pragma unroll
    for (int p = 0; p < 4; ++p)
#pragma unroll
        for (int c = 0; c < C; ++c) acc[p][c] = 0.f;

#pragma unroll 1
    for (int jb = 0; jb < 16; ++jb) {
        const int off = jb * 256 + lane * 4;
        float4 x0 = *reinterpret_cast<const float4*>(fp0 + off);
        float4 x1 = *reinterpret_cast<const float4*>(fp1 + off);
        float4 x2 = *reinterpret_cast<const float4*>(fp2 + off);
        float4 x3 = *reinterpret_cast<const float4*>(fp3 + off);
        int4 l = *reinterpret_cast<const int4*>(&sh.llab[(jb * 64 + lane) * 4]);
#pragma unroll
        for (int c = 0; c < C; ++c) {
            const float ohx = (l.x == c) ? 1.f : 0.f;
            const float ohy = (l.y == c) ? 1.f : 0.f;
            const float ohz = (l.z == c) ? 1.f : 0.f;
            const float ohw = (l.w == c) ? 1.f : 0.f;
            acc[0][c] = fmaf(ohx, x0.x, acc[0][c]);
            acc[0][c] = fmaf(ohy, x0.y, acc[0][c]);
            acc[0][c] = fmaf(ohz, x0.z, acc[0][c]);
            acc[0][c] = fmaf(ohw, x0.w, acc[0][c]);
            acc[1][c] = fmaf(ohx, x1.x, acc[1][c]);
            acc[1][c] = fmaf(ohy, x1.y, acc[1][c]);
            acc[1][c] = fmaf(ohz, x1.z, acc[1][c]);
            acc[1][c] = fmaf(ohw, x1.w, acc[1][c]);
            acc[2][c] = fmaf(ohx, x2.x, acc[2][c]);
            acc[2][c] = fmaf(ohy, x2.y, acc[2][c]);
            acc[2][c] = fmaf(ohz, x2.z, acc[2][c]);
            acc[2][c] = fmaf(ohw, x2.w, acc[2][c]);
            acc[3][c] = fmaf(ohx, x3.x, acc[3][c]);
            acc[3][c] = fmaf(ohy, x3.y, acc[3][c]);
            acc[3][c] = fmaf(ohz, x3.z, acc[3][c]);
            acc[3][c] = fmaf(ohw, x3.w, acc[3][c]);
        }
    }

    // wave-reduce 4x19 values, then one 19-lane atomic per plane
#pragma unroll
    for (int p = 0; p < 4; ++p) {
#pragma unroll
        for (int c = 0; c < C; ++c)
            for (int m = 1; m < 64; m <<= 1) acc[p][c] += __shfl_xor(acc[p][c], m);
        float v = acc[p][0];
#pragma unroll
        for (int c = 1; c < C; ++c) v = (lane == c) ? acc[p][c] : v;
        if (lane < C) atomicAdd(&ws[WS_SUMS + (dbase + p) * C + lane], v);
    }

    // ---- last-block-done ticket: the final finisher runs the old k2 ----
    __threadfence();   // order this block's atomics before the ticket (agent)
    if (t == 0) {
        unsigned tk = __hip_atomic_fetch_add(
            reinterpret_cast<unsigned*>(ws) + WS_TKT1, 1u,
            __ATOMIC_ACQ_REL, __HIP_MEMORY_SCOPE_AGENT);
        is_last = (tk == K1_NB - 1);
    }
    __syncthreads();   // also separates llab use from p2 union reuse
    if (!is_last) return;
    __threadfence();   // acquire side

    // ---------------- tail = old k2 (single block) ----------------
    if (t == 0) { sh.p2.lreg = 0.f; sh.p2.ldist = 0.f; }
    if (t < C) {
        float c = AGENT_LOAD(&ws[WS_CNT + t]);
        sh.p2.lcnt[t] = c;
        sh.p2.lvalid[t] = (c > 100.f) ? 1.f : 0.f;
    }
    __syncthreads();
    for (int i = t; i < DCH * C; i += TPB) {
        int c = i % C;
        float m = AGENT_LOAD(&ws[WS_SUMS + i]) / fmaxf(sh.p2.lcnt[c], 1.f);
        sh.p2.lm[i] = m;
        ws[WS_MEANS + i] = m;
    }
    if (t == 0) {
        float tv = 0.f; int last = -1;
        for (int c2 = 0; c2 < C; ++c2) if (sh.p2.lvalid[c2] > 0.5f) { tv += 1.f; last = c2; }
        sh.p2.ltv = tv; sh.p2.llast = last;
    }
    __syncthreads();
    if (t < C) {
        float s = 0.f;
        for (int d = 0; d < DCH; ++d) { float m = sh.p2.lm[d * C + t]; s += m * m; }
        float nrm = (s > 0.f) ? sqrtf(s) : 0.f;
        if (sh.p2.lvalid[t] > 0.5f) atomicAdd(&sh.p2.lreg, nrm);
    }
    for (int pr = t; pr < C * C; pr += TPB) {
        int a = pr / C, b2 = pr % C;
        if (sh.p2.lvalid[a] > 0.5f && sh.p2.lvalid[b2] > 0.5f && b2 != sh.p2.llast) {
            float s = 0.f;
            for (int d = 0; d < DCH; ++d) {
                float df = sh.p2.lm[d * C + a] - sh.p2.lm[d * C + b2];
                s += df * df;
            }
            float nrm = (s > 0.f) ? sqrtf(s) : 0.f;
            float hd = fmaxf(3.0f - nrm, 0.f);   // 2*DELTA_D = 3.0
            atomicAdd(&sh.p2.ldist, hd * hd);
        }
    }
    __syncthreads();
    if (t < C) ws[WS_VALID + t] = sh.p2.lvalid[t];
    if (t == 0) {
        ws[WS_SCAL + 0] = sh.p2.lreg;
        ws[WS_SCAL + 1] = sh.p2.ldist;
        ws[WS_SCAL + 2] = sh.p2.ltv;
    }
}

// ---------------------------------------------------------------------------
// Pass 3: per-pixel hinged distance to class mean; last-block tail = old k4.
// 2048 blocks x 256 thr. Thread = (quad, d-quarter): 32 independent float4
// loads, batched 8-deep. Partial sums combined across the 4 d-quarters with
// shfl_xor. Means in LDS padded to stride 20.
// ---------------------------------------------------------------------------
#define K3_NB 2048
#define MPAD 20

__global__ __launch_bounds__(TPB)
__attribute__((amdgpu_waves_per_eu(4, 4)))
void k3_var(const float* __restrict__ feats,
            const int* __restrict__ labels,
            float* __restrict__ ws,
            float* __restrict__ out) {
    __shared__ float lmS[DCH * MPAD];   // 10240 B, padded
    __shared__ float lvalid[C];
    __shared__ float lvar[C];
    __shared__ int is_last;
    const int t = threadIdx.x;
    for (int i = t; i < DCH * C; i += TPB) {
        int d = i / C, c = i - d * C;
        lmS[d * MPAD + c] = ws[WS_MEANS + i];   // prev dispatch: plain load ok
    }
    if (t < C) { lvalid[t] = ws[WS_VALID + t]; lvar[t] = 0.f; }
    __syncthreads();

    const int qloc = t >> 2;                 // 0..63
    const int k = t & 3;                     // d-quarter
    const int q = blockIdx.x * 64 + qloc;    // global quad
    const int b = q >> 14;                   // 16384 quads per image
    const int p = (q & 16383) * 4;

    const int4 lab4 = *reinterpret_cast<const int4*>(labels + b * HWSZ + p);
    const int l0 = lab4.x < 0 ? 0 : lab4.x;
    const int l1 = lab4.y < 0 ? 0 : lab4.y;
    const int l2 = lab4.z < 0 ? 0 : lab4.z;
    const int l3 = lab4.w < 0 ? 0 : lab4.w;

    const float* fb = feats + (((size_t)(b * DCH + k * 32)) << 16) + p;
    float a0 = 0.f, a1 = 0.f, a2 = 0.f, a3 = 0.f;
    for (int i = 0; i < 32; i += 8) {
        float4 xb[8];
#pragma unroll
        for (int u = 0; u < 8; ++u)
            xb[u] = *reinterpret_cast<const float4*>(fb + ((size_t)(i + u) << 16));
#pragma unroll
        for (int u = 0; u < 8; ++u) {
            const float* mr = &lmS[(k * 32 + i + u) * MPAD];
            float d0 = xb[u].x - mr[l0]; a0 = fmaf(d0, d0, a0);
            float d1 = xb[u].y - mr[l1]; a1 = fmaf(d1, d1, a1);
            float d2 = xb[u].z - mr[l2]; a2 = fmaf(d2, d2, a2);
            float d3 = xb[u].w - mr[l3]; a3 = fmaf(d3, d3, a3);
        }
    }
    // combine the 4 d-quarters (lanes t, t^1, t^2, t^3 share a quad)
    a0 += __shfl_xor(a0, 1); a0 += __shfl_xor(a0, 2);
    a1 += __shfl_xor(a1, 1); a1 += __shfl_xor(a1, 2);
    a2 += __shfl_xor(a2, 1); a2 += __shfl_xor(a2, 2);
    a3 += __shfl_xor(a3, 1); a3 += __shfl_xor(a3, 2);

    if (k == 0) {
        auto hinge2 = [&](float a, int rawlab, int l) -> float {
            float nrm = (a > 0.f) ? sqrtf(a) : 0.f;
            float h = fmaxf(nrm - 0.5f, 0.f);      // DELTA_V = 0.5
            float v = h * h;
            return (rawlab >= 0 && lvalid[l] > 0.5f) ? v : 0.f;
        };
        atomicAdd(&lvar[l0], hinge2(a0, lab4.x, l0));
        atomicAdd(&lvar[l1], hinge2(a1, lab4.y, l1));
        atomicAdd(&lvar[l2], hinge2(a2, lab4.z, l2));
        atomicAdd(&lvar[l3], hinge2(a3, lab4.w, l3));
    }
    __syncthreads();
    if (t < C) atomicAdd(&ws[WS_VAR + t], lvar[t]);

    // ---- last-block-done ticket: the final finisher runs the old k4 ----
    __threadfence();
    if (t == 0) {
        unsigned tk = __hip_atomic_fetch_add(
            reinterpret_cast<unsigned*>(ws) + WS_TKT2, 1u,
            __ATOMIC_ACQ_REL, __HIP_MEMORY_SCOPE_AGENT);
        is_last = (tk == K3_NB - 1);
    }
    __syncthreads();
    if (!is_last) return;

    if (t == 0) {
        __threadfence();
        float loss_var = 0.f;
        for (int c = 0; c < C; ++c) {
            float cnt = AGENT_LOAD(&ws[WS_CNT + c]);
            float v = AGENT_LOAD(&ws[WS_VAR + c]) / fmaxf(cnt, 1.f);
            if (ws[WS_VALID + c] > 0.5f) loss_var += v;
        }
        float reg  = ws[WS_SCAL + 0];
        float dist = ws[WS_SCAL + 1];
        float tv   = ws[WS_SCAL + 2];
        float loss = loss_var / tv + dist / (tv * (tv - 1.0f)) + 0.001f * reg / tv;
        out[0] = loss;
    }
}

extern "C" void kernel_launch(void* const* d_in, const int* in_sizes, int n_in,
                              void* d_out, int out_size, void* d_ws, size_t ws_size,
                              hipStream_t stream) {
    const float* feats  = (const float*)d_in[0];
    const int*   labels = (const int*)d_in[1];
    float* ws  = (float*)d_ws;
    float* out = (float*)d_out;

    hipMemsetAsync(ws, 0, WS_ZERO_END * sizeof(float), stream);
    hipLaunchKernelGGL(k1_sums, dim3(K1_NB), dim3(TPB), 0, stream, feats, labels, ws);
    hipLaunchKernelGGL(k3_var,  dim3(K3_NB), dim3(TPB), 0, stream, feats, labels, ws, out);
}

// Round 8
// 438.984 us; speedup vs baseline: 3.8073x; 3.8073x over previous
//
#include <hip/hip_runtime.h>

#define C 19
#define DCH 128
#define HWSZ 65536
#define TPB 256

// ws float offsets
#define WS_SUMS  0      // 2432 floats: sums[d*19+c]
#define WS_CNT   2432   // 19
#define WS_VAR   2451   // 19
#define WS_MEANS 2560   // 2432: means[d*19+c]
#define WS_VALID 4992   // 19
#define WS_SCAL  5011   // 3: loss_reg, loss_dist, t
#define WS_ZERO_END 2470

// ---------------------------------------------------------------------------
// Structure: memset + 4 kernels. Rounds 3-6 established that fusing the small
// passes into the hot kernels (cooperative launch, last-block ticket tails,
// waves_per_eu pins) wrecks hipcc's register allocation of the hot loops
// (VGPR 32 -> serialized loads 378us; VGPR 64 -> acc spills, 1.85 GB scratch
// writes, 961us). The plain multi-kernel split gets sane codegen (k1,k3 each
// <159us) and measured 442.4us total. Keep hot kernels UNTOUCHED by cold code.
// ---------------------------------------------------------------------------

// Pass 1: per-class sums + counts.
// 1024 blocks x 256 thr. Block = (image b, pixel-range r of 4096, d-group of 16).
// Each wave handles 4 consecutive planes; the 19-class one-hot is computed once
// per pixel-component and consumed by 4 fmaf's. Labels staged in LDS.
#define K1_NB  1024
#define K1_RPX 4096

__global__ __launch_bounds__(TPB) void k1_sums(const float* __restrict__ feats,
                                               const int* __restrict__ labels,
                                               float* __restrict__ ws) {
    __shared__ int llab[K1_RPX];   // 16 KB

    const int t = threadIdx.x;
    const int lane = t & 63;
    const int w = t >> 6;
    const int bid = blockIdx.x;
    const int b  = bid >> 7;          // 128 blocks per image
    const int r  = (bid >> 3) & 15;   // 16 ranges of 4096 px
    const int dg = bid & 7;           // 8 d-groups of 16 planes

    // stage labels (coalesced int4), keep own 16 in regs for counting
    const int* lb = labels + b * HWSZ + r * K1_RPX;
    int4 myl[4];
#pragma unroll
    for (int u = 0; u < 4; ++u) {
        int4 v = *reinterpret_cast<const int4*>(lb + (u * TPB + t) * 4);
        myl[u] = v;
        *reinterpret_cast<int4*>(&llab[(u * TPB + t) * 4]) = v;
    }
    __syncthreads();

    // counts: only dg==0 blocks contribute
    if (dg == 0) {
        float cr[C];
#pragma unroll
        for (int c = 0; c < C; ++c) cr[c] = 0.f;
#pragma unroll
        for (int u = 0; u < 4; ++u) {
#pragma unroll
            for (int c = 0; c < C; ++c) {
                cr[c] += (myl[u].x == c ? 1.f : 0.f);
                cr[c] += (myl[u].y == c ? 1.f : 0.f);
                cr[c] += (myl[u].z == c ? 1.f : 0.f);
                cr[c] += (myl[u].w == c ? 1.f : 0.f);
            }
        }
#pragma unroll
        for (int c = 0; c < C; ++c)
            for (int m = 1; m < 64; m <<= 1) cr[c] += __shfl_xor(cr[c], m);
        float v = cr[0];
#pragma unroll
        for (int c = 1; c < C; ++c) v = (lane == c) ? cr[c] : v;
        if (lane < C) atomicAdd(&ws[WS_CNT + lane], v);
    }

    // four consecutive d-planes per wave; one-hot shared across all 4
    const int dbase = dg * 16 + w * 4;
    const float* fp0 = feats + (((size_t)(b * DCH + dbase + 0)) << 16) + r * K1_RPX;
    const float* fp1 = feats + (((size_t)(b * DCH + dbase + 1)) << 16) + r * K1_RPX;
    const float* fp2 = feats + (((size_t)(b * DCH + dbase + 2)) << 16) + r * K1_RPX;
    const float* fp3 = feats + (((size_t)(b * DCH + dbase + 3)) << 16) + r * K1_RPX;

    float acc[4][C];
#pragma unroll
    for (int p = 0; p < 4; ++p)
#pragma unroll
        for (int c = 0; c < C; ++c) acc[p][c] = 0.f;

#pragma unroll 1
    for (int jb = 0; jb < 16; ++jb) {
        const int off = jb * 256 + lane * 4;
        float4 x0 = *reinterpret_cast<const float4*>(fp0 + off);
        float4 x1 = *reinterpret_cast<const float4*>(fp1 + off);
        float4 x2 = *reinterpret_cast<const float4*>(fp2 + off);
        float4 x3 = *reinterpret_cast<const float4*>(fp3 + off);
        int4 l = *reinterpret_cast<const int4*>(&llab[(jb * 64 + lane) * 4]);
#pragma unroll
        for (int c = 0; c < C; ++c) {
            const float ohx = (l.x == c) ? 1.f : 0.f;
            const float ohy = (l.y == c) ? 1.f : 0.f;
            const float ohz = (l.z == c) ? 1.f : 0.f;
            const float ohw = (l.w == c) ? 1.f : 0.f;
            acc[0][c] = fmaf(ohx, x0.x, acc[0][c]);
            acc[0][c] = fmaf(ohy, x0.y, acc[0][c]);
            acc[0][c] = fmaf(ohz, x0.z, acc[0][c]);
            acc[0][c] = fmaf(ohw, x0.w, acc[0][c]);
            acc[1][c] = fmaf(ohx, x1.x, acc[1][c]);
            acc[1][c] = fmaf(ohy, x1.y, acc[1][c]);
            acc[1][c] = fmaf(ohz, x1.z, acc[1][c]);
            acc[1][c] = fmaf(ohw, x1.w, acc[1][c]);
            acc[2][c] = fmaf(ohx, x2.x, acc[2][c]);
            acc[2][c] = fmaf(ohy, x2.y, acc[2][c]);
            acc[2][c] = fmaf(ohz, x2.z, acc[2][c]);
            acc[2][c] = fmaf(ohw, x2.w, acc[2][c]);
            acc[3][c] = fmaf(ohx, x3.x, acc[3][c]);
            acc[3][c] = fmaf(ohy, x3.y, acc[3][c]);
            acc[3][c] = fmaf(ohz, x3.z, acc[3][c]);
            acc[3][c] = fmaf(ohw, x3.w, acc[3][c]);
        }
    }

    // wave-reduce 4x19 values, then one 19-lane atomic per plane
#pragma unroll
    for (int p = 0; p < 4; ++p) {
#pragma unroll
        for (int c = 0; c < C; ++c)
            for (int m = 1; m < 64; m <<= 1) acc[p][c] += __shfl_xor(acc[p][c], m);
        float v = acc[p][0];
#pragma unroll
        for (int c = 1; c < C; ++c) v = (lane == c) ? acc[p][c] : v;
        if (lane < C) atomicAdd(&ws[WS_SUMS + (dbase + p) * C + lane], v);
    }
}

// Pass 2: means, valid mask, loss_reg, loss_dist, t. Single block.
__global__ __launch_bounds__(TPB) void k2_means(float* __restrict__ ws) {
    __shared__ float lm[DCH * C];
    __shared__ float lcnt[C];
    __shared__ float lvalid[C];
    __shared__ float lreg;
    __shared__ float ldist;
    __shared__ int   llast;
    __shared__ float ltv;
    int t = threadIdx.x;
    if (t == 0) { lreg = 0.f; ldist = 0.f; }
    if (t < C) {
        float c = ws[WS_CNT + t];
        lcnt[t] = c;
        lvalid[t] = (c > 100.f) ? 1.f : 0.f;
    }
    __syncthreads();
    for (int i = t; i < DCH * C; i += TPB) {
        int c = i % C;
        float m = ws[WS_SUMS + i] / fmaxf(lcnt[c], 1.f);
        lm[i] = m;
        ws[WS_MEANS + i] = m;
    }
    if (t == 0) {
        float tv = 0.f; int last = -1;
        for (int c2 = 0; c2 < C; ++c2) if (lvalid[c2] > 0.5f) { tv += 1.f; last = c2; }
        ltv = tv; llast = last;
    }
    __syncthreads();
    if (t < C) {
        float s = 0.f;
        for (int d = 0; d < DCH; ++d) { float m = lm[d * C + t]; s += m * m; }
        float nrm = (s > 0.f) ? sqrtf(s) : 0.f;
        if (lvalid[t] > 0.5f) atomicAdd(&lreg, nrm);
    }
    for (int pr = t; pr < C * C; pr += TPB) {
        int a = pr / C, b2 = pr % C;
        if (lvalid[a] > 0.5f && lvalid[b2] > 0.5f && b2 != llast) {
            float s = 0.f;
            for (int d = 0; d < DCH; ++d) {
                float df = lm[d * C + a] - lm[d * C + b2];
                s += df * df;
            }
            float nrm = (s > 0.f) ? sqrtf(s) : 0.f;
            float hd = fmaxf(3.0f - nrm, 0.f);   // 2*DELTA_D = 3.0
            atomicAdd(&ldist, hd * hd);
        }
    }
    __syncthreads();
    if (t < C) ws[WS_VALID + t] = lvalid[t];
    if (t == 0) {
        ws[WS_SCAL + 0] = lreg;
        ws[WS_SCAL + 1] = ldist;
        ws[WS_SCAL + 2] = ltv;
    }
}

// Pass 3: per-pixel hinged distance to class mean.
// 2048 blocks x 256 thr. Thread = (quad, d-quarter): 32 independent float4
// loads, batched 8-deep. Partial sums combined across the 4 d-quarters with
// shfl_xor. Means in LDS padded to stride 20.
#define K3_NB 2048
#define MPAD 20

__global__ __launch_bounds__(TPB) void k3_var(const float* __restrict__ feats,
                                              const int* __restrict__ labels,
                                              float* __restrict__ ws) {
    __shared__ float lmS[DCH * MPAD];   // 10240 B, padded
    __shared__ float lvalid[C];
    __shared__ float lvar[C];
    const int t = threadIdx.x;
    for (int i = t; i < DCH * C; i += TPB) {
        int d = i / C, c = i - d * C;
        lmS[d * MPAD + c] = ws[WS_MEANS + i];
    }
    if (t < C) { lvalid[t] = ws[WS_VALID + t]; lvar[t] = 0.f; }
    __syncthreads();

    const int qloc = t >> 2;                 // 0..63
    const int k = t & 3;                     // d-quarter
    const int q = blockIdx.x * 64 + qloc;    // global quad
    const int b = q >> 14;                   // 16384 quads per image
    const int p = (q & 16383) * 4;

    const int4 lab4 = *reinterpret_cast<const int4*>(labels + b * HWSZ + p);
    const int l0 = lab4.x < 0 ? 0 : lab4.x;
    const int l1 = lab4.y < 0 ? 0 : lab4.y;
    const int l2 = lab4.z < 0 ? 0 : lab4.z;
    const int l3 = lab4.w < 0 ? 0 : lab4.w;

    const float* fb = feats + (((size_t)(b * DCH + k * 32)) << 16) + p;
    float a0 = 0.f, a1 = 0.f, a2 = 0.f, a3 = 0.f;
    for (int i = 0; i < 32; i += 8) {
        float4 xb[8];
#pragma unroll
        for (int u = 0; u < 8; ++u)
            xb[u] = *reinterpret_cast<const float4*>(fb + ((size_t)(i + u) << 16));
#pragma unroll
        for (int u = 0; u < 8; ++u) {
            const float* mr = &lmS[(k * 32 + i + u) * MPAD];
            float d0 = xb[u].x - mr[l0]; a0 = fmaf(d0, d0, a0);
            float d1 = xb[u].y - mr[l1]; a1 = fmaf(d1, d1, a1);
            float d2 = xb[u].z - mr[l2]; a2 = fmaf(d2, d2, a2);
            float d3 = xb[u].w - mr[l3]; a3 = fmaf(d3, d3, a3);
        }
    }
    // combine the 4 d-quarters (lanes t, t^1, t^2, t^3 share a quad)
    a0 += __shfl_xor(a0, 1); a0 += __shfl_xor(a0, 2);
    a1 += __shfl_xor(a1, 1); a1 += __shfl_xor(a1, 2);
    a2 += __shfl_xor(a2, 1); a2 += __shfl_xor(a2, 2);
    a3 += __shfl_xor(a3, 1); a3 += __shfl_xor(a3, 2);

    if (k == 0) {
        auto hinge2 = [&](float a, int rawlab, int l) -> float {
            float nrm = (a > 0.f) ? sqrtf(a) : 0.f;
            float h = fmaxf(nrm - 0.5f, 0.f);      // DELTA_V = 0.5
            float v = h * h;
            return (rawlab >= 0 && lvalid[l] > 0.5f) ? v : 0.f;
        };
        atomicAdd(&lvar[l0], hinge2(a0, lab4.x, l0));
        atomicAdd(&lvar[l1], hinge2(a1, lab4.y, l1));
        atomicAdd(&lvar[l2], hinge2(a2, lab4.z, l2));
        atomicAdd(&lvar[l3], hinge2(a3, lab4.w, l3));
    }
    __syncthreads();
    if (t < C) atomicAdd(&ws[WS_VAR + t], lvar[t]);
}

// Pass 4: final scalar.
__global__ void k4_final(const float* __restrict__ ws, float* __restrict__ out) {
    if (threadIdx.x == 0) {
        float loss_var = 0.f;
        for (int c = 0; c < C; ++c) {
            float cnt = ws[WS_CNT + c];
            float v = ws[WS_VAR + c] / fmaxf(cnt, 1.f);
            if (ws[WS_VALID + c] > 0.5f) loss_var += v;
        }
        float reg  = ws[WS_SCAL + 0];
        float dist = ws[WS_SCAL + 1];
        float tv   = ws[WS_SCAL + 2];
        float loss = loss_var / tv + dist / (tv * (tv - 1.0f)) + 0.001f * reg / tv;
        out[0] = loss;
    }
}

extern "C" void kernel_launch(void* const* d_in, const int* in_sizes, int n_in,
                              void* d_out, int out_size, void* d_ws, size_t ws_size,
                              hipStream_t stream) {
    const float* feats  = (const float*)d_in[0];
    const int*   labels = (const int*)d_in[1];
    float* ws  = (float*)d_ws;
    float* out = (float*)d_out;

    hipMemsetAsync(ws, 0, WS_ZERO_END * sizeof(float), stream);
    hipLaunchKernelGGL(k1_sums,  dim3(K1_NB), dim3(TPB), 0, stream, feats, labels, ws);
    hipLaunchKernelGGL(k2_means, dim3(1),   dim3(TPB), 0, stream, ws);
    hipLaunchKernelGGL(k3_var,   dim3(K3_NB), dim3(TPB), 0, stream, feats, labels, ws);
    hipLaunchKernelGGL(k4_final, dim3(1),   dim3(64),  0, stream, ws, out);
}